// Round 22
// baseline (137.292 us; speedup 1.0000x reference)
//
#include <hip/hip_runtime.h>
#include <hip/hip_bf16.h>
#include <stdint.h>

#define T_SEQ 2048
#define DIMSZ 1024
#define NH    16
#define HDIM  64
#define NBATCH 2
#define KVB   64
#define ATT_SCALE 0.12f
#define QSCALE (0.12f * 1.4426950408889634f)

typedef __attribute__((ext_vector_type(8))) __bf16 bf16x8;
typedef __attribute__((ext_vector_type(8))) ushort u16x8;
typedef __attribute__((ext_vector_type(4))) float f32x4;
typedef __attribute__((ext_vector_type(16))) float f32x16;

#define GLOAD_LDS16(gp, lp)                                                            \
  __builtin_amdgcn_global_load_lds((const __attribute__((address_space(1))) void*)(gp),\
                                   (__attribute__((address_space(3))) void*)(lp),      \
                                   16, 0, 0)

__device__ __forceinline__ ushort f2bf(float f) {
  union { float f; uint32_t u; } v; v.f = f;
  uint32_t u = v.u;
  uint32_t r = (u + 0x7FFFu + ((u >> 16) & 1u)) >> 16;
  return (ushort)r;
}

__device__ __forceinline__ float bf2f(ushort h) {
  union { float f; uint32_t u; } v;
  v.u = ((uint32_t)h) << 16;
  return v.f;
}

// paired f32->bf16 (compiler fuses into v_cvt_pk_bf16_f32)
__device__ __forceinline__ uint32_t pk2(float a, float b) {
  union { __hip_bfloat162 h; uint32_t u; } cv;
  cv.h = __hip_bfloat162(__float2bfloat16(a), __float2bfloat16(b));
  return cv.u;
}

// ---------------- merged prep: conv(x), conv(w), rope tables (one launch) ----------------
__global__ __launch_bounds__(256) void prep_k(const float* __restrict__ x,
                                              const float* __restrict__ w,
                                              ushort* __restrict__ Xb,
                                              ushort* __restrict__ Wb,
                                              float* __restrict__ ctab,
                                              float* __restrict__ stab) {
  int bid = blockIdx.x;
  int tid = threadIdx.x;
  if (bid < 4096) {
    int i = (bid * 256 + tid) * 4;
    float4 v = *(const float4*)(x + i);
    ushort4 o;
    o.x = f2bf(v.x); o.y = f2bf(v.y); o.z = f2bf(v.z); o.w = f2bf(v.w);
    *(ushort4*)(Xb + i) = o;
  } else if (bid < 8192) {
    int i = ((bid - 4096) * 256 + tid) * 4;
    float4 v = *(const float4*)(w + i);
    ushort4 o;
    o.x = f2bf(v.x); o.y = f2bf(v.y); o.z = f2bf(v.z); o.w = f2bf(v.w);
    *(ushort4*)(Wb + i) = o;
  } else {
    int idx = (bid - 8192) * 256 + tid;  // t*32 + j
    int j = idx & 31, t = idx >> 5;
    float c = 1.f, s = 0.f;
    if (j < 16) {
      float inv = powf(1024.0f, -(float)j / 15.0f);
      float th = (float)t * inv;
      c = cosf(th);
      s = sinf(th);
    }
    ctab[idx] = c;
    stab[idx] = s;
  }
}

#define BM 128
#define BN 128
#define BKS 64

// ---------------- QKV GEMM: 128^2 + swizzle + fused epilogue v2 (measured 77us) ----------
__global__ __launch_bounds__(256) void gemm_qkv_k(const ushort* __restrict__ A,
                                                  const ushort* __restrict__ Bt,
                                                  const float* __restrict__ ve,
                                                  const float* __restrict__ lam,
                                                  const float* __restrict__ ctab,
                                                  const float* __restrict__ stab,
                                                  ushort* __restrict__ Qb,
                                                  ushort* __restrict__ Kb,
                                                  ushort* __restrict__ Vt) {
  const int K = DIMSZ;
  __shared__ __align__(16) ushort As[BM * BKS];
  __shared__ __align__(16) ushort Bs[BN * BKS];
  int tid = threadIdx.x;
  int wave = tid >> 6, lane = tid & 63;
  int lr = lane & 15, lg = lane >> 4;
  int m0 = blockIdx.x * BM, n0 = blockIdx.y * BN;
  int wm = (wave >> 1) * 64, wn = (wave & 1) * 64;

  int srow = tid >> 3;
  int sel = (((tid & 7) ^ (srow & 7)) << 3);  // pre-swizzled source column

  f32x4 acc[4][4];
  for (int m = 0; m < 4; ++m)
    for (int n = 0; n < 4; ++n)
      acc[m][n] = (f32x4){0.f, 0.f, 0.f, 0.f};

  for (int k0 = 0; k0 < K; k0 += BKS) {
#pragma unroll
    for (int it = 0; it < 4; ++it) {
      GLOAD_LDS16(A + (size_t)(m0 + it * 32 + srow) * K + k0 + sel, &As[(it * 256 + tid) * 8]);
      GLOAD_LDS16(Bt + (size_t)(n0 + it * 32 + srow) * K + k0 + sel, &Bs[(it * 256 + tid) * 8]);
    }
    __syncthreads();
#pragma unroll
    for (int kk = 0; kk < 2; ++kk) {
      int cA = (((kk * 4 + lg) ^ (lr & 7)) << 3);
      bf16x8 af[4], bf[4];
#pragma unroll
      for (int m = 0; m < 4; ++m)
        af[m] = *(const bf16x8*)&As[(wm + m * 16 + lr) * BKS + cA];
#pragma unroll
      for (int n = 0; n < 4; ++n)
        bf[n] = *(const bf16x8*)&Bs[(wn + n * 16 + lr) * BKS + cA];
#pragma unroll
      for (int m = 0; m < 4; ++m)
#pragma unroll
        for (int n = 0; n < 4; ++n)
          acc[m][n] = __builtin_amdgcn_mfma_f32_16x16x32_bf16(af[m], bf[n], acc[m][n], 0, 0, 0);
    }
    __syncthreads();
  }

  // ---- epilogue v2: per-wave LDS transpose to token-ownership ----
  int sec = n0 >> 10;                   // 0=Q, 1=K, 2=V (block-uniform)
  int h = ((n0 & 1023) + wn) >> 6;      // head (wave-uniform)
  ushort* Tl = (wave < 2 ? As : Bs) + (wave & 1) * 4096;

#pragma unroll
  for (int m = 0; m < 4; ++m)
#pragma unroll
    for (int n = 0; n < 4; ++n)
#pragma unroll
      for (int r = 0; r < 4; ++r) {
        int tl = m * 16 + lg * 4 + r;
        int d = n * 16 + lr;
        Tl[tl * 64 + ((((d >> 3) ^ (tl & 7)) << 3) | (d & 7))] = f2bf(acc[m][n][r]);
      }

  int tl = lane;
  float xv[64];
#pragma unroll
  for (int j = 0; j < 8; ++j) {
    u16x8 rw = *(const u16x8*)&Tl[tl * 64 + ((j ^ (tl & 7)) << 3)];
#pragma unroll
    for (int e = 0; e < 8; ++e) xv[j * 8 + e] = bf2f((ushort)rw[e]);
  }

  float ss = 0.f;
#pragma unroll
  for (int i = 0; i < 64; ++i) ss += xv[i] * xv[i];
  float rinv = rsqrtf(ss * (1.0f / 64.0f) + 1e-6f);
#pragma unroll
  for (int i = 0; i < 64; ++i) xv[i] *= rinv;

  int row = m0 + wm + tl;               // token id 0..4095
  int t = row & (T_SEQ - 1);
  int bb = row >> 11;
  int bh = bb * NH + h;

  if (sec < 2) {
    float cs[16], sn[16];
    const float4* cp = (const float4*)(ctab + t * 32);
    const float4* sp = (const float4*)(stab + t * 32);
#pragma unroll
    for (int j = 0; j < 4; ++j) {
      float4 c4 = cp[j], s4 = sp[j];
      cs[j * 4 + 0] = c4.x; cs[j * 4 + 1] = c4.y; cs[j * 4 + 2] = c4.z; cs[j * 4 + 3] = c4.w;
      sn[j * 4 + 0] = s4.x; sn[j * 4 + 1] = s4.y; sn[j * 4 + 2] = s4.z; sn[j * 4 + 3] = s4.w;
    }
#pragma unroll
    for (int j = 0; j < 16; ++j) {
      float a = xv[j], bv = xv[j + 32];
      xv[j] = a * cs[j] + bv * sn[j];
      xv[j + 32] = bv * cs[j] - a * sn[j];
    }
    float sc = (sec == 0) ? QSCALE : 1.0f;
    ushort* dst = (sec == 0 ? Qb : Kb) + ((size_t)bh * T_SEQ + t) * HDIM;
#pragma unroll
    for (int p = 0; p < 8; ++p) {
      uint4 wq = make_uint4(pk2(xv[8 * p] * sc, xv[8 * p + 1] * sc),
                            pk2(xv[8 * p + 2] * sc, xv[8 * p + 3] * sc),
                            pk2(xv[8 * p + 4] * sc, xv[8 * p + 5] * sc),
                            pk2(xv[8 * p + 6] * sc, xv[8 * p + 7] * sc));
      *((uint4*)dst + p) = wq;
    }
  } else {
    float l0 = lam[0], l1 = lam[1];
    const float4* vp = (const float4*)(ve + ((size_t)(bb * T_SEQ + t)) * DIMSZ + h * HDIM);
#pragma unroll
    for (int j = 0; j < 16; ++j) {
      float4 vv4 = vp[j];
      xv[j * 4 + 0] = l0 * xv[j * 4 + 0] + l1 * vv4.x;
      xv[j * 4 + 1] = l0 * xv[j * 4 + 1] + l1 * vv4.y;
      xv[j * 4 + 2] = l0 * xv[j * 4 + 2] + l1 * vv4.z;
      xv[j * 4 + 3] = l0 * xv[j * 4 + 3] + l1 * vv4.w;
    }
    ushort* dst = Vt + (size_t)bh * HDIM * T_SEQ + t;
#pragma unroll
    for (int i = 0; i < 64; ++i)
      dst[(size_t)i * T_SEQ] = f2bf(xv[i]);
  }
}

// ---------------- out-projection GEMM: 64x128 tile, 2 blocks/CU ----------------
__global__ __launch_bounds__(256) void gemm_out_k(const ushort* __restrict__ A,
                                                  const ushort* __restrict__ Bt,
                                                  float* __restrict__ C) {
  const int K = DIMSZ, N = DIMSZ;
  __shared__ __align__(16) ushort As[64 * BKS];   // 8 KB
  __shared__ __align__(16) ushort Bs[128 * BKS];  // 16 KB
  int tid = threadIdx.x;
  int wave = tid >> 6, lane = tid & 63;
  int lr = lane & 15, lg = lane >> 4;
  int m0 = blockIdx.x * 64, n0 = blockIdx.y * 128;
  int wm = (wave >> 1) * 32, wn = (wave & 1) * 64;

  int srow = tid >> 3;
  int sel = (((tid & 7) ^ (srow & 7)) << 3);  // pre-swizzled source column

  f32x4 acc[2][4];
#pragma unroll
  for (int m = 0; m < 2; ++m)
#pragma unroll
    for (int n = 0; n < 4; ++n)
      acc[m][n] = (f32x4){0.f, 0.f, 0.f, 0.f};

  for (int k0 = 0; k0 < K; k0 += BKS) {
#pragma unroll
    for (int it = 0; it < 2; ++it)
      GLOAD_LDS16(A + (size_t)(m0 + it * 32 + srow) * K + k0 + sel, &As[(it * 256 + tid) * 8]);
#pragma unroll
    for (int it = 0; it < 4; ++it)
      GLOAD_LDS16(Bt + (size_t)(n0 + it * 32 + srow) * K + k0 + sel, &Bs[(it * 256 + tid) * 8]);
    __syncthreads();
#pragma unroll
    for (int kk = 0; kk < 2; ++kk) {
      int cA = (((kk * 4 + lg) ^ (lr & 7)) << 3);
      bf16x8 af[2], bf[4];
#pragma unroll
      for (int m = 0; m < 2; ++m)
        af[m] = *(const bf16x8*)&As[(wm + m * 16 + lr) * BKS + cA];
#pragma unroll
      for (int n = 0; n < 4; ++n)
        bf[n] = *(const bf16x8*)&Bs[(wn + n * 16 + lr) * BKS + cA];
#pragma unroll
      for (int m = 0; m < 2; ++m)
#pragma unroll
        for (int n = 0; n < 4; ++n)
          acc[m][n] = __builtin_amdgcn_mfma_f32_16x16x32_bf16(af[m], bf[n], acc[m][n], 0, 0, 0);
    }
    __syncthreads();
  }
#pragma unroll
  for (int m = 0; m < 2; ++m)
#pragma unroll
    for (int n = 0; n < 4; ++n)
#pragma unroll
      for (int r = 0; r < 4; ++r) {
        int row = m0 + wm + m * 16 + lg * 4 + r;
        int col = n0 + wn + n * 16 + lr;
        C[(size_t)row * N + col] = acc[m][n][r];
      }
}

// ---------------- flash attention v6: 32x32 MFMA, 2 waves x 32 q-rows per block ----------
// Same grid/balance as v3 (64-row q-tile per block, heavy-first); only wave width
// changes: each wave computes a 32-q-row tile with mfma_f32_32x32x16_bf16, so each
// K/V fragment LDS read feeds 2x the q-rows -> per-q-row LDS-pipe bytes HALVE (the
// R17-measured bottleneck). Layouts: A/B frag row=l&31, k=(l>>5)*8+i (contiguous-8
// convention, mirrors the verified 16x16 pattern); C/D col=l&31,
// row=(reg&3)+8*(reg>>2)+4*(l>>5) (guide-verified m74/m101).
// LDS = 16+16+8 KB = 40960 -> 4 blocks/CU (8 waves).
__global__ __launch_bounds__(128) void attn_k(const ushort* __restrict__ Q,
                                              const ushort* __restrict__ K,
                                              const ushort* __restrict__ Vt,
                                              ushort* __restrict__ Y) {
  int bh = blockIdx.x;       // 0..31 -> dispatch id % 8 = bh % 8 (XCD L2 locality)
  int qb = 31 - blockIdx.y;  // 64-row q-tile, heavy blocks first
  int tid = threadIdx.x;     // 0..127, 2 waves
  int wid = tid >> 6, lane = tid & 63;
  int l5 = lane >> 5;        // 0/1: k-slice group
  int q = lane & 31;         // q-column within wave tile
  int b = bh >> 4, h = bh & 15;

  int r0 = qb * 64 + wid * 32;  // this wave's 32 q-rows
  int nkv = qb + 1;

  __shared__ __align__(16) ushort Kl[2][KVB * HDIM];   // 2 x 8 KB  [key][dim]
  __shared__ __align__(16) ushort Vl[2][KVB * HDIM];   // 2 x 8 KB  [d][key]
  __shared__ __align__(16) ushort Plds[2][32][64];     // 8 KB, per-wave [q][key] swz

  const ushort* Kbh = K + (size_t)bh * T_SEQ * HDIM;
  const ushort* Vbh = Vt + (size_t)bh * HDIM * T_SEQ;

  // staging: 128 threads, 4 instr/array: thread t -> row sr=t>>3 (+16j), chunk t&7
  int sr = tid >> 3;
  int sel = (((tid & 7) ^ (sr & 7)) << 3);
  const ushort* ksrc = Kbh + (size_t)sr * HDIM + sel;
  const ushort* vsrc = Vbh + (size_t)sr * T_SEQ + sel;
  int ldb = tid * 8;  // + j*1024 elements

  // Q B-fragments: B[k=dim-slice][col=q]: bq[s] = Q[r0+q][s*16 + l5*8 .. +8]
  const ushort* Qrow = Q + ((size_t)bh * T_SEQ + r0 + q) * HDIM;
  bf16x8 bq[4];
#pragma unroll
  for (int s = 0; s < 4; ++s)
    bq[s] = *(const bf16x8*)(Qrow + s * 16 + l5 * 8);

  f32x16 o0 = {0}, o1 = {0};  // O^T[d-block 0/1][q]
  float lrow = 0.f;

  // prologue: stage tile 0 into buffer 0
#pragma unroll
  for (int j = 0; j < 4; ++j) {
    GLOAD_LDS16(ksrc + (size_t)j * 16 * HDIM, &Kl[0][ldb + j * 1024]);
    GLOAD_LDS16(vsrc + (size_t)j * 16 * T_SEQ, &Vl[0][ldb + j * 1024]);
  }
  __syncthreads();

  for (int kb = 0; kb < nkv; ++kb) {
    int cur = kb & 1;
    if (kb + 1 < nkv) {
      size_t ko = (size_t)(kb + 1) * KVB * HDIM;
      int vo = (kb + 1) * KVB;
#pragma unroll
      for (int j = 0; j < 4; ++j) {
        GLOAD_LDS16(ksrc + ko + (size_t)j * 16 * HDIM, &Kl[cur ^ 1][ldb + j * 1024]);
        GLOAD_LDS16(vsrc + vo + (size_t)j * 16 * T_SEQ, &Vl[cur ^ 1][ldb + j * 1024]);
      }
    }
    const ushort* Kc = &Kl[cur][0];
    const ushort* Vc = &Vl[cur][0];

    // QK^T: S^T[h32][key 32][q 32], halves h32=0,1; k-slices s over 64 dims
    f32x16 s0 = {0}, s1 = {0};
    __builtin_amdgcn_s_setprio(1);
#pragma unroll
    for (int s = 0; s < 4; ++s) {
      int cA = (((s * 2 + l5) ^ (q & 7)) << 3);
      bf16x8 kf0 = *(const bf16x8*)&Kc[(0 * 32 + q) * 64 + cA];
      s0 = __builtin_amdgcn_mfma_f32_32x32x16_bf16(kf0, bq[s], s0, 0, 0, 0);
      bf16x8 kf1 = *(const bf16x8*)&Kc[(1 * 32 + q) * 64 + cA];
      s1 = __builtin_amdgcn_mfma_f32_32x32x16_bf16(kf1, bq[s], s1, 0, 0, 0);
    }
    __builtin_amdgcn_s_setprio(0);

    // causal mask on the diagonal tile (scores pre-scaled via Q)
    if (kb == nkv - 1) {
      int qrow = r0 + q;
      int kb0 = kb * KVB + 4 * l5;
#pragma unroll
      for (int reg = 0; reg < 16; ++reg) {
        int kidx = kb0 + (reg & 3) + 8 * (reg >> 2);
        if (kidx > qrow) s0[reg] = -1e30f;
        if (kidx + 32 > qrow) s1[reg] = -1e30f;
      }
    }
    // P = exp2(S) (static shift: |arg| <= 11.08 after RMSNorm); lane-partial sum;
    // pack 4-key groups as uint2 into swizzled Plds[q][key]
    float psum = 0.f;
#pragma unroll
    for (int hh = 0; hh < 2; ++hh) {
#pragma unroll
      for (int g = 0; g < 4; ++g) {
        float p0, p1, p2, p3;
        if (hh == 0) {
          p0 = exp2f(s0[4 * g + 0]); p1 = exp2f(s0[4 * g + 1]);
          p2 = exp2f(s0[4 * g + 2]); p3 = exp2f(s0[4 * g + 3]);
        } else {
          p0 = exp2f(s1[4 * g + 0]); p1 = exp2f(s1[4 * g + 1]);
          p2 = exp2f(s1[4 * g + 2]); p3 = exp2f(s1[4 * g + 3]);
        }
        psum += (p0 + p1) + (p2 + p3);
        uint2 w;
        w.x = pk2(p0, p1);
        w.y = pk2(p2, p3);
        *(uint2*)&Plds[wid][q][(((g + 4 * hh) ^ (q & 7)) << 3) + 4 * l5] = w;
      }
    }
    lrow += psum;
    // PV: O^T[db][q] += V^T[db][key] . P[key][q], k-slices s' over 64 keys
    __builtin_amdgcn_s_setprio(1);
#pragma unroll
    for (int s = 0; s < 4; ++s) {
      bf16x8 bp = *(const bf16x8*)&Plds[wid][q][((s * 2 + l5) ^ (q & 7)) << 3];
      int cV = (((s * 2 + l5) ^ (q & 7)) << 3);
      bf16x8 vf0 = *(const bf16x8*)&Vc[(0 * 32 + q) * 64 + cV];
      o0 = __builtin_amdgcn_mfma_f32_32x32x16_bf16(vf0, bp, o0, 0, 0, 0);
      bf16x8 vf1 = *(const bf16x8*)&Vc[(1 * 32 + q) * 64 + cV];
      o1 = __builtin_amdgcn_mfma_f32_32x32x16_bf16(vf1, bp, o1, 0, 0, 0);
    }
    __builtin_amdgcn_s_setprio(0);
    __syncthreads();  // staging landed + buf[cur] consumed
  }
  // epilogue: complete row sum (lanes q and q+32 share a row), normalize, write
  lrow += __shfl_xor(lrow, 32);
  float inv = 1.0f / lrow;
  int row = r0 + q;
  ushort* dst = Y + ((size_t)b * T_SEQ + row) * DIMSZ + h * HDIM;
#pragma unroll
  for (int db = 0; db < 2; ++db)
#pragma unroll
    for (int g = 0; g < 4; ++g) {
      float v0, v1, v2, v3;
      if (db == 0) {
        v0 = o0[4 * g + 0]; v1 = o0[4 * g + 1]; v2 = o0[4 * g + 2]; v3 = o0[4 * g + 3];
      } else {
        v0 = o1[4 * g + 0]; v1 = o1[4 * g + 1]; v2 = o1[4 * g + 2]; v3 = o1[4 * g + 3];
      }
      uint2 w;
      w.x = pk2(v0 * inv, v1 * inv);
      w.y = pk2(v2 * inv, v3 * inv);
      *(uint2*)&dst[8 * g + 4 * l5 + 32 * db] = w;
    }
}

// ---------------- launch ----------------
extern "C" void kernel_launch(void* const* d_in, const int* in_sizes, int n_in,
                              void* d_out, int out_size, void* d_ws, size_t ws_size,
                              hipStream_t stream) {
  const float* x   = (const float*)d_in[0];
  const float* ve  = (const float*)d_in[1];
  const float* lam = (const float*)d_in[2];
  const float* w   = (const float*)d_in[4];  // (4, 1024, 1024)
  float* out = (float*)d_out;

  char* ws = (char*)d_ws;

  ushort* Xb   = (ushort*)(ws);                        // 8 MB  @ 0
  ushort* Wb   = (ushort*)(ws + 8388608);              // 8 MB  @ 8M
  ushort* Qb   = (ushort*)(ws + 16777216);             // 8 MB  @ 16M
  ushort* Kb   = (ushort*)(ws + 25165824);             // 8 MB  @ 24M
  ushort* Vt   = (ushort*)(ws + 33554432);             // 8 MB  @ 32M
  ushort* Yb   = (ushort*)(ws + 41943040);             // 8 MB  @ 40M
  float*  ctab = (float*)(ws + 50331648);              // 256 KB @ 48M
  float*  stab = (float*)(ws + 50593792);              // 256 KB

  // merged prep: x-conv (4096 blks) + w-conv (4096) + rope tables (256)
  prep_k<<<8448, 256, 0, stream>>>(x, w, Xb, Wb, ctab, stab);

  // QKV GEMM (4096 x 3072 x 1024), 128^2 + swizzle, fused epilogue (measured 77us)
  gemm_qkv_k<<<dim3(4096 / BM, 3072 / BN), 256, 0, stream>>>(Xb, Wb, ve, lam, ctab, stab,
                                                             Qb, Kb, Vt);

  // attention v6: 32x32 MFMA, 2 waves x 32 q-rows, 64-row q-tile per block
  attn_k<<<dim3(NBATCH * NH, 32), 128, 0, stream>>>(Qb, Kb, Vt, Yb);

  // out-proj: (4096 x 1024) = Yb @ W3^T, 64x128 tiles (512 blocks, 2/CU)
  gemm_out_k<<<dim3(4096 / 64, 1024 / 128), 256, 0, stream>>>(Yb, Wb + 3ull * DIMSZ * DIMSZ, out);
}

// Round 23
// 117.820 us; speedup vs baseline: 1.1653x; 1.1653x over previous
//
#include <hip/hip_runtime.h>
#include <hip/hip_bf16.h>
#include <stdint.h>

#define T_SEQ 2048
#define DIMSZ 1024
#define NH    16
#define HDIM  64
#define NBATCH 2
#define KVB   64
#define ATT_SCALE 0.12f
#define QSCALE (0.12f * 1.4426950408889634f)

typedef __attribute__((ext_vector_type(8))) __bf16 bf16x8;
typedef __attribute__((ext_vector_type(8))) ushort u16x8;
typedef __attribute__((ext_vector_type(4))) float f32x4;

#define GLOAD_LDS16(gp, lp)                                                            \
  __builtin_amdgcn_global_load_lds((const __attribute__((address_space(1))) void*)(gp),\
                                   (__attribute__((address_space(3))) void*)(lp),      \
                                   16, 0, 0)

__device__ __forceinline__ ushort f2bf(float f) {
  union { float f; uint32_t u; } v; v.f = f;
  uint32_t u = v.u;
  uint32_t r = (u + 0x7FFFu + ((u >> 16) & 1u)) >> 16;
  return (ushort)r;
}

__device__ __forceinline__ float bf2f(ushort h) {
  union { float f; uint32_t u; } v;
  v.u = ((uint32_t)h) << 16;
  return v.f;
}

// paired f32->bf16 (compiler fuses into v_cvt_pk_bf16_f32)
__device__ __forceinline__ uint32_t pk2(float a, float b) {
  union { __hip_bfloat162 h; uint32_t u; } cv;
  cv.h = __hip_bfloat162(__float2bfloat16(a), __float2bfloat16(b));
  return cv.u;
}

// ---------------- merged prep: conv(x), conv(w), rope tables (one launch) ----------------
__global__ __launch_bounds__(256) void prep_k(const float* __restrict__ x,
                                              const float* __restrict__ w,
                                              ushort* __restrict__ Xb,
                                              ushort* __restrict__ Wb,
                                              float* __restrict__ ctab,
                                              float* __restrict__ stab) {
  int bid = blockIdx.x;
  int tid = threadIdx.x;
  if (bid < 4096) {
    int i = (bid * 256 + tid) * 4;
    float4 v = *(const float4*)(x + i);
    ushort4 o;
    o.x = f2bf(v.x); o.y = f2bf(v.y); o.z = f2bf(v.z); o.w = f2bf(v.w);
    *(ushort4*)(Xb + i) = o;
  } else if (bid < 8192) {
    int i = ((bid - 4096) * 256 + tid) * 4;
    float4 v = *(const float4*)(w + i);
    ushort4 o;
    o.x = f2bf(v.x); o.y = f2bf(v.y); o.z = f2bf(v.z); o.w = f2bf(v.w);
    *(ushort4*)(Wb + i) = o;
  } else {
    int idx = (bid - 8192) * 256 + tid;  // t*32 + j
    int j = idx & 31, t = idx >> 5;
    float c = 1.f, s = 0.f;
    if (j < 16) {
      float inv = powf(1024.0f, -(float)j / 15.0f);
      float th = (float)t * inv;
      c = cosf(th);
      s = sinf(th);
    }
    ctab[idx] = c;
    stab[idx] = s;
  }
}

#define BM 128
#define BN 128
#define BKS 64

// ---------------- QKV GEMM: 128^2 + swizzle + fused epilogue v2 (measured 77us) ----------
__global__ __launch_bounds__(256) void gemm_qkv_k(const ushort* __restrict__ A,
                                                  const ushort* __restrict__ Bt,
                                                  const float* __restrict__ ve,
                                                  const float* __restrict__ lam,
                                                  const float* __restrict__ ctab,
                                                  const float* __restrict__ stab,
                                                  ushort* __restrict__ Qb,
                                                  ushort* __restrict__ Kb,
                                                  ushort* __restrict__ Vt) {
  const int K = DIMSZ;
  __shared__ __align__(16) ushort As[BM * BKS];
  __shared__ __align__(16) ushort Bs[BN * BKS];
  int tid = threadIdx.x;
  int wave = tid >> 6, lane = tid & 63;
  int lr = lane & 15, lg = lane >> 4;
  int m0 = blockIdx.x * BM, n0 = blockIdx.y * BN;
  int wm = (wave >> 1) * 64, wn = (wave & 1) * 64;

  int srow = tid >> 3;
  int sel = (((tid & 7) ^ (srow & 7)) << 3);  // pre-swizzled source column

  f32x4 acc[4][4];
  for (int m = 0; m < 4; ++m)
    for (int n = 0; n < 4; ++n)
      acc[m][n] = (f32x4){0.f, 0.f, 0.f, 0.f};

  for (int k0 = 0; k0 < K; k0 += BKS) {
#pragma unroll
    for (int it = 0; it < 4; ++it) {
      GLOAD_LDS16(A + (size_t)(m0 + it * 32 + srow) * K + k0 + sel, &As[(it * 256 + tid) * 8]);
      GLOAD_LDS16(Bt + (size_t)(n0 + it * 32 + srow) * K + k0 + sel, &Bs[(it * 256 + tid) * 8]);
    }
    __syncthreads();
#pragma unroll
    for (int kk = 0; kk < 2; ++kk) {
      int cA = (((kk * 4 + lg) ^ (lr & 7)) << 3);
      bf16x8 af[4], bf[4];
#pragma unroll
      for (int m = 0; m < 4; ++m)
        af[m] = *(const bf16x8*)&As[(wm + m * 16 + lr) * BKS + cA];
#pragma unroll
      for (int n = 0; n < 4; ++n)
        bf[n] = *(const bf16x8*)&Bs[(wn + n * 16 + lr) * BKS + cA];
#pragma unroll
      for (int m = 0; m < 4; ++m)
#pragma unroll
        for (int n = 0; n < 4; ++n)
          acc[m][n] = __builtin_amdgcn_mfma_f32_16x16x32_bf16(af[m], bf[n], acc[m][n], 0, 0, 0);
    }
    __syncthreads();
  }

  // ---- epilogue v2: per-wave LDS transpose to token-ownership ----
  int sec = n0 >> 10;                   // 0=Q, 1=K, 2=V (block-uniform)
  int h = ((n0 & 1023) + wn) >> 6;      // head (wave-uniform)
  ushort* Tl = (wave < 2 ? As : Bs) + (wave & 1) * 4096;

#pragma unroll
  for (int m = 0; m < 4; ++m)
#pragma unroll
    for (int n = 0; n < 4; ++n)
#pragma unroll
      for (int r = 0; r < 4; ++r) {
        int tl = m * 16 + lg * 4 + r;
        int d = n * 16 + lr;
        Tl[tl * 64 + ((((d >> 3) ^ (tl & 7)) << 3) | (d & 7))] = f2bf(acc[m][n][r]);
      }

  int tl = lane;
  float xv[64];
#pragma unroll
  for (int j = 0; j < 8; ++j) {
    u16x8 rw = *(const u16x8*)&Tl[tl * 64 + ((j ^ (tl & 7)) << 3)];
#pragma unroll
    for (int e = 0; e < 8; ++e) xv[j * 8 + e] = bf2f((ushort)rw[e]);
  }

  float ss = 0.f;
#pragma unroll
  for (int i = 0; i < 64; ++i) ss += xv[i] * xv[i];
  float rinv = rsqrtf(ss * (1.0f / 64.0f) + 1e-6f);
#pragma unroll
  for (int i = 0; i < 64; ++i) xv[i] *= rinv;

  int row = m0 + wm + tl;               // token id 0..4095
  int t = row & (T_SEQ - 1);
  int bb = row >> 11;
  int bh = bb * NH + h;

  if (sec < 2) {
    float cs[16], sn[16];
    const float4* cp = (const float4*)(ctab + t * 32);
    const float4* sp = (const float4*)(stab + t * 32);
#pragma unroll
    for (int j = 0; j < 4; ++j) {
      float4 c4 = cp[j], s4 = sp[j];
      cs[j * 4 + 0] = c4.x; cs[j * 4 + 1] = c4.y; cs[j * 4 + 2] = c4.z; cs[j * 4 + 3] = c4.w;
      sn[j * 4 + 0] = s4.x; sn[j * 4 + 1] = s4.y; sn[j * 4 + 2] = s4.z; sn[j * 4 + 3] = s4.w;
    }
#pragma unroll
    for (int j = 0; j < 16; ++j) {
      float a = xv[j], bv = xv[j + 32];
      xv[j] = a * cs[j] + bv * sn[j];
      xv[j + 32] = bv * cs[j] - a * sn[j];
    }
    float sc = (sec == 0) ? QSCALE : 1.0f;
    ushort* dst = (sec == 0 ? Qb : Kb) + ((size_t)bh * T_SEQ + t) * HDIM;
#pragma unroll
    for (int p = 0; p < 8; ++p) {
      uint4 wq = make_uint4(pk2(xv[8 * p] * sc, xv[8 * p + 1] * sc),
                            pk2(xv[8 * p + 2] * sc, xv[8 * p + 3] * sc),
                            pk2(xv[8 * p + 4] * sc, xv[8 * p + 5] * sc),
                            pk2(xv[8 * p + 6] * sc, xv[8 * p + 7] * sc));
      *((uint4*)dst + p) = wq;
    }
  } else {
    float l0 = lam[0], l1 = lam[1];
    const float4* vp = (const float4*)(ve + ((size_t)(bb * T_SEQ + t)) * DIMSZ + h * HDIM);
#pragma unroll
    for (int j = 0; j < 16; ++j) {
      float4 vv4 = vp[j];
      xv[j * 4 + 0] = l0 * xv[j * 4 + 0] + l1 * vv4.x;
      xv[j * 4 + 1] = l0 * xv[j * 4 + 1] + l1 * vv4.y;
      xv[j * 4 + 2] = l0 * xv[j * 4 + 2] + l1 * vv4.z;
      xv[j * 4 + 3] = l0 * xv[j * 4 + 3] + l1 * vv4.w;
    }
    ushort* dst = Vt + (size_t)bh * HDIM * T_SEQ + t;
#pragma unroll
    for (int i = 0; i < 64; ++i)
      dst[(size_t)i * T_SEQ] = f2bf(xv[i]);
  }
}

// ---------------- out-projection GEMM: 64x128 tile, 2 blocks/CU ----------------
__global__ __launch_bounds__(256) void gemm_out_k(const ushort* __restrict__ A,
                                                  const ushort* __restrict__ Bt,
                                                  float* __restrict__ C) {
  const int K = DIMSZ, N = DIMSZ;
  __shared__ __align__(16) ushort As[64 * BKS];   // 8 KB
  __shared__ __align__(16) ushort Bs[128 * BKS];  // 16 KB
  int tid = threadIdx.x;
  int wave = tid >> 6, lane = tid & 63;
  int lr = lane & 15, lg = lane >> 4;
  int m0 = blockIdx.x * 64, n0 = blockIdx.y * 128;
  int wm = (wave >> 1) * 32, wn = (wave & 1) * 64;

  int srow = tid >> 3;
  int sel = (((tid & 7) ^ (srow & 7)) << 3);  // pre-swizzled source column

  f32x4 acc[2][4];
#pragma unroll
  for (int m = 0; m < 2; ++m)
#pragma unroll
    for (int n = 0; n < 4; ++n)
      acc[m][n] = (f32x4){0.f, 0.f, 0.f, 0.f};

  for (int k0 = 0; k0 < K; k0 += BKS) {
#pragma unroll
    for (int it = 0; it < 2; ++it)
      GLOAD_LDS16(A + (size_t)(m0 + it * 32 + srow) * K + k0 + sel, &As[(it * 256 + tid) * 8]);
#pragma unroll
    for (int it = 0; it < 4; ++it)
      GLOAD_LDS16(Bt + (size_t)(n0 + it * 32 + srow) * K + k0 + sel, &Bs[(it * 256 + tid) * 8]);
    __syncthreads();
#pragma unroll
    for (int kk = 0; kk < 2; ++kk) {
      int cA = (((kk * 4 + lg) ^ (lr & 7)) << 3);
      bf16x8 af[2], bf[4];
#pragma unroll
      for (int m = 0; m < 2; ++m)
        af[m] = *(const bf16x8*)&As[(wm + m * 16 + lr) * BKS + cA];
#pragma unroll
      for (int n = 0; n < 4; ++n)
        bf[n] = *(const bf16x8*)&Bs[(wn + n * 16 + lr) * BKS + cA];
#pragma unroll
      for (int m = 0; m < 2; ++m)
#pragma unroll
        for (int n = 0; n < 4; ++n)
          acc[m][n] = __builtin_amdgcn_mfma_f32_16x16x32_bf16(af[m], bf[n], acc[m][n], 0, 0, 0);
    }
    __syncthreads();
  }
#pragma unroll
  for (int m = 0; m < 2; ++m)
#pragma unroll
    for (int n = 0; n < 4; ++n)
#pragma unroll
      for (int r = 0; r < 4; ++r) {
        int row = m0 + wm + m * 16 + lg * 4 + r;
        int col = n0 + wn + n * 16 + lr;
        C[(size_t)row * N + col] = acc[m][n][r];
      }
}

// ---------------- flash attention v3 + T5 setprio (R21 banked best) ----------------
__global__ __launch_bounds__(256, 3) void attn_k(const ushort* __restrict__ Q,
                                                 const ushort* __restrict__ K,
                                                 const ushort* __restrict__ Vt,
                                                 ushort* __restrict__ Y) {
  int bh = blockIdx.x;       // 0..31 -> dispatch id % 8 = bh % 8 (XCD L2 locality)
  int qb = 31 - blockIdx.y;  // heavy blocks dispatch first
  int tid = threadIdx.x;
  int wid = tid >> 6, lane = tid & 63;
  int lr = lane & 15, lg = lane >> 4;
  int b = bh >> 4, h = bh & 15;

  int r0 = qb * 64 + wid * 16;
  int nkv = qb + 1;

  __shared__ __align__(16) ushort Kl[2][KVB * HDIM];   // 2 x 8 KB
  __shared__ __align__(16) ushort Vl[2][KVB * HDIM];   // 2 x 8 KB ([d=64][key=64])
  __shared__ __align__(16) ushort Plds[4][16][72];

  const ushort* Kbh = K + (size_t)bh * T_SEQ * HDIM;
  const ushort* Vbh = Vt + (size_t)bh * HDIM * T_SEQ;

  int sr = tid >> 3;
  int sel = (((tid & 7) ^ (sr & 7)) << 3);
  const ushort* ksrc0 = Kbh + (size_t)sr * HDIM + sel;
  const ushort* ksrc1 = Kbh + (size_t)(sr + 32) * HDIM + sel;
  const ushort* vsrc0 = Vbh + (size_t)sr * T_SEQ + sel;
  const ushort* vsrc1 = Vbh + (size_t)(sr + 32) * T_SEQ + sel;
  int ld0 = tid * 8, ld1 = tid * 8 + 2048;  // element offsets

  const ushort* Qbase = Q + ((size_t)bh * T_SEQ + r0) * HDIM;
  bf16x8 aq[2];
#pragma unroll
  for (int kk = 0; kk < 2; ++kk)
    aq[kk] = *(const bf16x8*)(Qbase + (size_t)lr * HDIM + kk * 32 + lg * 8);

  int fcol[2];
  fcol[0] = ((0 + lg) ^ (lr & 7)) << 3;
  fcol[1] = ((4 + lg) ^ (lr & 7)) << 3;

  f32x4 o[4];
#pragma unroll
  for (int n = 0; n < 4; ++n) o[n] = (f32x4){0.f, 0.f, 0.f, 0.f};
  float lrow = 0.f;

  GLOAD_LDS16(ksrc0, &Kl[0][ld0]);
  GLOAD_LDS16(ksrc1, &Kl[0][ld1]);
  GLOAD_LDS16(vsrc0, &Vl[0][ld0]);
  GLOAD_LDS16(vsrc1, &Vl[0][ld1]);
  __syncthreads();

  for (int kb = 0; kb < nkv; ++kb) {
    int cur = kb & 1;
    if (kb + 1 < nkv) {
      size_t ko = (size_t)(kb + 1) * KVB * HDIM;
      int vo = (kb + 1) * KVB;
      GLOAD_LDS16(ksrc0 + ko, &Kl[cur ^ 1][ld0]);
      GLOAD_LDS16(ksrc1 + ko, &Kl[cur ^ 1][ld1]);
      GLOAD_LDS16(vsrc0 + vo, &Vl[cur ^ 1][ld0]);
      GLOAD_LDS16(vsrc1 + vo, &Vl[cur ^ 1][ld1]);
    }
    const ushort* Kc = &Kl[cur][0];
    const ushort* Vc = &Vl[cur][0];
    f32x4 s[4];
    __builtin_amdgcn_s_setprio(1);
#pragma unroll
    for (int n = 0; n < 4; ++n) {
      f32x4 a = (f32x4){0.f, 0.f, 0.f, 0.f};
      bf16x8 kf0 = *(const bf16x8*)&Kc[(n * 16 + lr) * HDIM + fcol[0]];
      a = __builtin_amdgcn_mfma_f32_16x16x32_bf16(kf0, aq[0], a, 0, 0, 0);
      bf16x8 kf1 = *(const bf16x8*)&Kc[(n * 16 + lr) * HDIM + fcol[1]];
      a = __builtin_amdgcn_mfma_f32_16x16x32_bf16(kf1, aq[1], a, 0, 0, 0);
      s[n] = a;
    }
    __builtin_amdgcn_s_setprio(0);
    if (kb == nkv - 1) {
      int qrow = r0 + lr;
      int kb0 = kb * KVB + lg * 4;
#pragma unroll
      for (int n = 0; n < 4; ++n)
#pragma unroll
        for (int r = 0; r < 4; ++r)
          if (kb0 + n * 16 + r > qrow) s[n][r] = -1e30f;
    }
    float psum = 0.f;
#pragma unroll
    for (int n = 0; n < 4; ++n) {
      float p0 = exp2f(s[n][0]), p1 = exp2f(s[n][1]);
      float p2 = exp2f(s[n][2]), p3 = exp2f(s[n][3]);
      psum += (p0 + p1) + (p2 + p3);
      uint2 w;
      w.x = pk2(p0, p1);
      w.y = pk2(p2, p3);
      *(uint2*)&Plds[wid][lr][n * 16 + lg * 4] = w;
    }
    lrow += psum;
    __builtin_amdgcn_s_setprio(1);
#pragma unroll
    for (int kk = 0; kk < 2; ++kk) {
      bf16x8 ap = *(const bf16x8*)&Plds[wid][lr][kk * 32 + lg * 8];
#pragma unroll
      for (int n = 0; n < 4; ++n) {
        bf16x8 vf = *(const bf16x8*)&Vc[(n * 16 + lr) * HDIM + fcol[kk]];
        o[n] = __builtin_amdgcn_mfma_f32_16x16x32_bf16(vf, ap, o[n], 0, 0, 0);
      }
    }
    __builtin_amdgcn_s_setprio(0);
    __syncthreads();
  }
  lrow += __shfl_xor(lrow, 16);
  lrow += __shfl_xor(lrow, 32);
  float inv = 1.0f / lrow;
  int row = r0 + lr;
#pragma unroll
  for (int n = 0; n < 4; ++n) {
    uint2 w;
    w.x = pk2(o[n][0] * inv, o[n][1] * inv);
    w.y = pk2(o[n][2] * inv, o[n][3] * inv);
    *(uint2*)&Y[((size_t)b * T_SEQ + row) * DIMSZ + h * HDIM + n * 16 + lg * 4] = w;
  }
}

// ---------------- launch ----------------
extern "C" void kernel_launch(void* const* d_in, const int* in_sizes, int n_in,
                              void* d_out, int out_size, void* d_ws, size_t ws_size,
                              hipStream_t stream) {
  const float* x   = (const float*)d_in[0];
  const float* ve  = (const float*)d_in[1];
  const float* lam = (const float*)d_in[2];
  const float* w   = (const float*)d_in[4];  // (4, 1024, 1024)
  float* out = (float*)d_out;

  char* ws = (char*)d_ws;

  ushort* Xb   = (ushort*)(ws);                        // 8 MB  @ 0
  ushort* Wb   = (ushort*)(ws + 8388608);              // 8 MB  @ 8M
  ushort* Qb   = (ushort*)(ws + 16777216);             // 8 MB  @ 16M
  ushort* Kb   = (ushort*)(ws + 25165824);             // 8 MB  @ 24M
  ushort* Vt   = (ushort*)(ws + 33554432);             // 8 MB  @ 32M
  ushort* Yb   = (ushort*)(ws + 41943040);             // 8 MB  @ 40M
  float*  ctab = (float*)(ws + 50331648);              // 256 KB @ 48M
  float*  stab = (float*)(ws + 50593792);              // 256 KB

  // merged prep: x-conv (4096 blks) + w-conv (4096) + rope tables (256)
  prep_k<<<8448, 256, 0, stream>>>(x, w, Xb, Wb, ctab, stab);

  // QKV GEMM (4096 x 3072 x 1024), 128^2 + swizzle, fused epilogue (measured 77us)
  gemm_qkv_k<<<dim3(4096 / BM, 3072 / BN), 256, 0, stream>>>(Xb, Wb, ve, lam, ctab, stab,
                                                             Qb, Kb, Vt);

  // attention v3 + setprio: one q-tile per block, heavy-first, 3 blocks/CU
  attn_k<<<dim3(NBATCH * NH, 32), 256, 0, stream>>>(Qb, Kb, Vt, Yb);

  // out-proj: (4096 x 1024) = Yb @ W3^T, 64x128 tiles (512 blocks, 2/CU)
  gemm_out_k<<<dim3(4096 / 64, 1024 / 128), 256, 0, stream>>>(Yb, Wb + 3ull * DIMSZ * DIMSZ, out);
}